// Round 1
// baseline (625.336 us; speedup 1.0000x reference)
//
#include <hip/hip_runtime.h>
#include <hip/hip_bf16.h>

// DirectedEdgeEncoder: out[e, :] = relu(concat(x[row[e]], edge_attr[e]) @ W^T + b)
// E=800000, D_NODE=D_EDGE=64, D_IN=128, D_OUT=128. fp32 in/out, bf16 MFMA compute.
//
// Strategy: tall-skinny GEMM, memory-bound (~630 MB HBM traffic vs 26 GFLOP).
// One wave per 16-edge tile. m-dim = output channels (8 tiles of 16),
// n-dim = edges (16), K = 128 (4 chunks of 32), v_mfma_f32_16x16x32_bf16.
// W fragments live in registers (loaded once per wave, 128 VGPRs); edge data
// streamed straight from global (coalesced 128B/row segments), no LDS.

typedef short bf16x8 __attribute__((ext_vector_type(8)));  // 8 bf16 in 4 VGPRs
typedef float f32x4  __attribute__((ext_vector_type(4)));

__device__ __forceinline__ short f2bf(float f) {
    // round-to-nearest-even fp32 -> bf16 (inputs are finite, no NaN handling)
    union { float f; unsigned int u; } v; v.f = f;
    unsigned int r = v.u + 0x7FFFu + ((v.u >> 16) & 1u);
    return (short)(r >> 16);
}

__device__ __forceinline__ bf16x8 pack8(f32x4 a, f32x4 b) {
    bf16x8 o;
    o[0] = f2bf(a[0]); o[1] = f2bf(a[1]); o[2] = f2bf(a[2]); o[3] = f2bf(a[3]);
    o[4] = f2bf(b[0]); o[5] = f2bf(b[1]); o[6] = f2bf(b[2]); o[7] = f2bf(b[3]);
    return o;
}

#define D_NODE 64
#define D_EDGE 64
#define D_IN   128
#define D_OUT  128

__global__ __launch_bounds__(256, 2)
void edge_encoder_kernel(const float* __restrict__ x,
                         const float* __restrict__ ea,
                         const int*   __restrict__ row_idx,   // edge_index[0][:]
                         const float* __restrict__ W,         // [D_OUT][D_IN] row-major
                         const float* __restrict__ bias,      // [D_OUT]
                         float*       __restrict__ out,       // [E][D_OUT]
                         int n_tiles)                          // E/16
{
    const int lane = threadIdx.x & 63;
    const int el   = lane & 15;   // n-index (edge within tile) / m-index (chan within W frag)
    const int quad = lane >> 4;   // 0..3

    // ---- Preload W as MFMA A-operand fragments: A[m=lane&15][k=quad*8+j] ----
    // wf[mt][kc] holds W[mt*16 + el][kc*32 + quad*8 + 0..7]
    bf16x8 wf[8][4];
#pragma unroll
    for (int mt = 0; mt < 8; ++mt) {
#pragma unroll
        for (int kc = 0; kc < 4; ++kc) {
            const float* p = W + (mt * 16 + el) * D_IN + kc * 32 + quad * 8;
            f32x4 w0 = *(const f32x4*)p;
            f32x4 w1 = *(const f32x4*)(p + 4);
            wf[mt][kc] = pack8(w0, w1);
        }
    }

    // ---- Preload bias in C/D layout: row = quad*4 + r -> channel mt*16+quad*4+r ----
    f32x4 bfr[8];
#pragma unroll
    for (int mt = 0; mt < 8; ++mt)
        bfr[mt] = *(const f32x4*)(bias + mt * 16 + quad * 4);

    const int wid = (int)((blockIdx.x * blockDim.x + threadIdx.x) >> 6);
    const int nw  = (int)((gridDim.x * blockDim.x) >> 6);

    for (int tile = wid; tile < n_tiles; tile += nw) {
        const int e = tile * 16 + el;          // this lane's edge (B-operand n-index)
        const int r = row_idx[e];              // gathered source node

        // B-operand fragments: B[k=quad*8+j][n=el] = feat[e][kc*32 + quad*8 + j]
        const float* xp = x  + (size_t)r * D_NODE + quad * 8;
        const float* ap = ea + (size_t)e * D_EDGE + quad * 8;
        f32x4 x0 = *(const f32x4*)(xp);
        f32x4 x1 = *(const f32x4*)(xp + 4);
        f32x4 x2 = *(const f32x4*)(xp + 32);
        f32x4 x3 = *(const f32x4*)(xp + 36);
        f32x4 a0 = *(const f32x4*)(ap);
        f32x4 a1 = *(const f32x4*)(ap + 4);
        f32x4 a2 = *(const f32x4*)(ap + 32);
        f32x4 a3 = *(const f32x4*)(ap + 36);

        bf16x8 ef[4];
        ef[0] = pack8(x0, x1);   // k   0..31  (node feats)
        ef[1] = pack8(x2, x3);   // k  32..63
        ef[2] = pack8(a0, a1);   // k  64..95  (edge feats)
        ef[3] = pack8(a2, a3);   // k  96..127

        f32x4 acc[8];
#pragma unroll
        for (int mt = 0; mt < 8; ++mt) acc[mt] = bfr[mt];

#pragma unroll
        for (int kc = 0; kc < 4; ++kc) {
#pragma unroll
            for (int mt = 0; mt < 8; ++mt) {
                acc[mt] = __builtin_amdgcn_mfma_f32_16x16x32_bf16(
                    wf[mt][kc], ef[kc], acc[mt], 0, 0, 0);
            }
        }

        // D layout: col = lane&15 = edge, row = quad*4 + reg = channel-in-tile
        // -> lane stores 4 consecutive channels per mt as one dwordx4
        float* op = out + (size_t)e * D_OUT + quad * 4;
#pragma unroll
        for (int mt = 0; mt < 8; ++mt) {
            f32x4 v = acc[mt];
            v[0] = fmaxf(v[0], 0.0f);
            v[1] = fmaxf(v[1], 0.0f);
            v[2] = fmaxf(v[2], 0.0f);
            v[3] = fmaxf(v[3], 0.0f);
            *(f32x4*)(op + mt * 16) = v;
        }
    }
}

extern "C" void kernel_launch(void* const* d_in, const int* in_sizes, int n_in,
                              void* d_out, int out_size, void* d_ws, size_t ws_size,
                              hipStream_t stream) {
    const float* x   = (const float*)d_in[0];   // [N, 64]
    const float* ea  = (const float*)d_in[1];   // [E, 64]
    const int*   ei  = (const int*)  d_in[2];   // [2, E] -> row = first E ints
    const float* W   = (const float*)d_in[3];   // [128, 128]
    const float* b   = (const float*)d_in[4];   // [128]
    float*       out = (float*)d_out;           // [E, 128]

    const int E = in_sizes[1] / D_EDGE;         // 800000
    const int n_tiles = E / 16;                 // 50000 (E % 16 == 0)

    dim3 block(256);
    dim3 grid(1024);
    edge_encoder_kernel<<<grid, block, 0, stream>>>(x, ea, ei, W, b, out, n_tiles);
}

// Round 2
// 619.813 us; speedup vs baseline: 1.0089x; 1.0089x over previous
//
#include <hip/hip_runtime.h>
#include <hip/hip_bf16.h>

// DirectedEdgeEncoder: out[e, :] = relu(concat(x[row[e]], edge_attr[e]) @ W^T + b)
// E=800000, D_NODE=D_EDGE=64, D_IN=128, D_OUT=128. fp32 in/out, bf16 MFMA compute.
//
// R2: wave-pair split of output channels to kill VGPR spill (R1 needed ~270
// regs > 256 cap -> scratch spill -> 625us). Even wave: ch 0-63, odd wave:
// ch 64-127, same 16-edge tile; pair shares L1 for the gathered edge data.
// ~160 VGPRs/wave. Nontemporal output stores keep x/ea resident in L2.

typedef short bf16x8 __attribute__((ext_vector_type(8)));  // 8 bf16 in 4 VGPRs
typedef float f32x4  __attribute__((ext_vector_type(4)));

__device__ __forceinline__ short f2bf(float f) {
    // round-to-nearest-even fp32 -> bf16 (inputs finite, no NaN handling)
    union { float f; unsigned int u; } v; v.f = f;
    unsigned int r = v.u + 0x7FFFu + ((v.u >> 16) & 1u);
    return (short)(r >> 16);
}

__device__ __forceinline__ bf16x8 pack8(f32x4 a, f32x4 b) {
    bf16x8 o;
    o[0] = f2bf(a[0]); o[1] = f2bf(a[1]); o[2] = f2bf(a[2]); o[3] = f2bf(a[3]);
    o[4] = f2bf(b[0]); o[5] = f2bf(b[1]); o[6] = f2bf(b[2]); o[7] = f2bf(b[3]);
    return o;
}

#define D_NODE 64
#define D_EDGE 64
#define D_IN   128
#define D_OUT  128

__global__ __launch_bounds__(256, 2)
void edge_encoder_kernel(const float* __restrict__ x,
                         const float* __restrict__ ea,
                         const int*   __restrict__ row_idx,   // edge_index[0][:]
                         const float* __restrict__ W,         // [D_OUT][D_IN] row-major
                         const float* __restrict__ bias,      // [D_OUT]
                         float*       __restrict__ out,       // [E][D_OUT]
                         int n_tiles)                          // E/16
{
    const int lane = threadIdx.x & 63;
    const int el   = lane & 15;   // edge-in-tile (B n-index) / channel-in-mt (A m-index)
    const int quad = lane >> 4;   // 0..3

    const int wid  = (int)((blockIdx.x * blockDim.x + threadIdx.x) >> 6);
    const int nw   = (int)((gridDim.x * blockDim.x) >> 6);
    const int half = wid & 1;            // 0: channels 0-63, 1: channels 64-127
    const int pair = wid >> 1;           // tile-pair id
    const int npair = nw >> 1;
    const int ch0  = half * 64;

    // ---- Preload this half's W as A-operand fragments: A[m=lane&15][k=quad*8+j]
    // wf[mt][kc] = W[ch0 + mt*16 + el][kc*32 + quad*8 + 0..7]   (64 VGPRs)
    bf16x8 wf[4][4];
#pragma unroll
    for (int mt = 0; mt < 4; ++mt) {
#pragma unroll
        for (int kc = 0; kc < 4; ++kc) {
            const float* p = W + (ch0 + mt * 16 + el) * D_IN + kc * 32 + quad * 8;
            f32x4 w0 = *(const f32x4*)p;
            f32x4 w1 = *(const f32x4*)(p + 4);
            wf[mt][kc] = pack8(w0, w1);
        }
    }

    // ---- Bias in C/D layout: row = quad*4 + r -> channel ch0 + mt*16 + quad*4 + r
    f32x4 bfr[4];
#pragma unroll
    for (int mt = 0; mt < 4; ++mt)
        bfr[mt] = *(const f32x4*)(bias + ch0 + mt * 16 + quad * 4);

    for (int tile = pair; tile < n_tiles; tile += npair) {
        const int e = tile * 16 + el;          // this lane's edge (B-operand n-index)
        const int r = row_idx[e];              // gathered source node

        // B-operand fragments: B[k=quad*8+j][n=el] = feat[e][kc*32 + quad*8 + j]
        const float* xp = x  + (size_t)r * D_NODE + quad * 8;
        const float* ap = ea + (size_t)e * D_EDGE + quad * 8;
        f32x4 x0 = *(const f32x4*)(xp);
        f32x4 x1 = *(const f32x4*)(xp + 4);
        f32x4 x2 = *(const f32x4*)(xp + 32);
        f32x4 x3 = *(const f32x4*)(xp + 36);
        f32x4 a0 = *(const f32x4*)(ap);
        f32x4 a1 = *(const f32x4*)(ap + 4);
        f32x4 a2 = *(const f32x4*)(ap + 32);
        f32x4 a3 = *(const f32x4*)(ap + 36);

        bf16x8 ef[4];
        ef[0] = pack8(x0, x1);   // k   0..31  (node feats)
        ef[1] = pack8(x2, x3);   // k  32..63
        ef[2] = pack8(a0, a1);   // k  64..95  (edge feats)
        ef[3] = pack8(a2, a3);   // k  96..127

        f32x4 acc[4];
#pragma unroll
        for (int mt = 0; mt < 4; ++mt) acc[mt] = bfr[mt];

#pragma unroll
        for (int kc = 0; kc < 4; ++kc) {
#pragma unroll
            for (int mt = 0; mt < 4; ++mt) {
                acc[mt] = __builtin_amdgcn_mfma_f32_16x16x32_bf16(
                    wf[mt][kc], ef[kc], acc[mt], 0, 0, 0);
            }
        }

        // D layout: col = lane&15 = edge, row = quad*4 + reg = channel-in-tile
        float* op = out + (size_t)e * D_OUT + ch0 + quad * 4;
#pragma unroll
        for (int mt = 0; mt < 4; ++mt) {
            f32x4 v = acc[mt];
            v[0] = fmaxf(v[0], 0.0f);
            v[1] = fmaxf(v[1], 0.0f);
            v[2] = fmaxf(v[2], 0.0f);
            v[3] = fmaxf(v[3], 0.0f);
            __builtin_nontemporal_store(v, (f32x4*)(op + mt * 16));
        }
    }
}

extern "C" void kernel_launch(void* const* d_in, const int* in_sizes, int n_in,
                              void* d_out, int out_size, void* d_ws, size_t ws_size,
                              hipStream_t stream) {
    const float* x   = (const float*)d_in[0];   // [N, 64]
    const float* ea  = (const float*)d_in[1];   // [E, 64]
    const int*   ei  = (const int*)  d_in[2];   // [2, E] -> row = first E ints
    const float* W   = (const float*)d_in[3];   // [128, 128]
    const float* b   = (const float*)d_in[4];   // [128]
    float*       out = (float*)d_out;           // [E, 128]

    const int E = in_sizes[1] / D_EDGE;         // 800000
    const int n_tiles = E / 16;                 // 50000 (E % 16 == 0)

    dim3 block(256);
    dim3 grid(512);   // 2048 waves = 1024 pairs, all co-resident, 48-49 tiles/pair
    edge_encoder_kernel<<<grid, block, 0, stream>>>(x, ea, ei, W, b, out, n_tiles);
}